// Round 2
// baseline (348.982 us; speedup 1.0000x reference)
//
#include <hip/hip_runtime.h>
#include <stdint.h>

#define EMBED 1024
#define NHEAD 16
#define HD    64
#define SEQ   2048
#define BATCH 4

typedef __bf16 bf16x8 __attribute__((ext_vector_type(8)));
typedef float  f32x4  __attribute__((ext_vector_type(4)));
typedef unsigned int u32x2 __attribute__((ext_vector_type(2)));

#define GLB(p)  ((__attribute__((address_space(1))) unsigned int*)(p))
#define LDSP(p) ((__attribute__((address_space(3))) unsigned int*)(p))
#define MFMA(a,b,c) __builtin_amdgcn_mfma_f32_16x16x32_bf16(a,b,c,0,0,0)

__device__ __forceinline__ unsigned int f2bf(float f) {
    unsigned int u = __float_as_uint(f);
    return (u + 0x7FFFu + ((u >> 16) & 1u)) >> 16;   // RNE fp32->bf16
}
__device__ __forceinline__ unsigned int pack2(float a, float b) {
    return f2bf(a) | (f2bf(b) << 16);
}

// ---------------- x fp32 -> bf16 ----------------
__global__ void k_convert(const float* __restrict__ in, unsigned short* __restrict__ out, int n4) {
    int i = blockIdx.x * 256 + threadIdx.x;
    if (i >= n4) return;
    f32x4 v = ((const f32x4*)in)[i];
    u32x2 w = { pack2(v[0], v[1]), pack2(v[2], v[3]) };
    ((u32x2*)out)[i] = w;
}

// ---------------- W [K][C] fp32 -> Wt [C][K] bf16 (LDS-tiled transpose) ----------------
__global__ void k_transpose(const float* __restrict__ in, unsigned short* __restrict__ out, int K, int C) {
    __shared__ float t[32][33];
    int c0 = blockIdx.x * 32, k0 = blockIdx.y * 32;
    int tid = threadIdx.x;
    #pragma unroll
    for (int i = 0; i < 4; i++) {
        int e = tid + i * 256;
        t[e >> 5][e & 31] = in[(size_t)(k0 + (e >> 5)) * C + c0 + (e & 31)];
    }
    __syncthreads();
    #pragma unroll
    for (int i = 0; i < 4; i++) {
        int e = tid + i * 256;
        int cl = e >> 5, kl = e & 31;
        out[(size_t)(c0 + cl) * K + k0 + kl] = (unsigned short)f2bf(t[kl][cl]);
    }
}

// ---------------- QKV GEMM + bias + RoPE, writes Q,K [bh][n][64] (Q pre-scaled), V^T [bh][64][n] ----------------
__global__ __launch_bounds__(256) void k_qkv(const unsigned short* __restrict__ xb,
    const unsigned short* __restrict__ wt, const float* __restrict__ bias,
    const float* __restrict__ rc, const float* __restrict__ rs,
    unsigned short* __restrict__ Qb, unsigned short* __restrict__ Kb, unsigned short* __restrict__ Vt)
{
    __shared__ unsigned short Al[128 * 32];
    __shared__ unsigned short Bl[128 * 32];
    const int tid = threadIdx.x;
    const int wave = tid >> 6, lane = tid & 63;
    const int l15 = lane & 15, l4 = lane >> 4;
    const int wr = wave >> 1, wc = wave & 1;
    const int tm = blockIdx.y * 128, tc = blockIdx.x * 128;

    const int srow = wave * 32 + (lane >> 2);
    const int scol = (lane & 3) * 8;
    const unsigned short* ga = xb + (size_t)(tm + srow) * EMBED + scol;
    const unsigned short* gb = wt + (size_t)(tc + srow) * EMBED + scol;

    f32x4 acc[4][4] = {};
    for (int k0 = 0; k0 < EMBED; k0 += 32) {
        __syncthreads();
        __builtin_amdgcn_global_load_lds(GLB(ga + k0),               LDSP(Al + wave * 1024),       16, 0, 0);
        __builtin_amdgcn_global_load_lds(GLB(ga + k0 + 16 * EMBED),  LDSP(Al + wave * 1024 + 512), 16, 0, 0);
        __builtin_amdgcn_global_load_lds(GLB(gb + k0),               LDSP(Bl + wave * 1024),       16, 0, 0);
        __builtin_amdgcn_global_load_lds(GLB(gb + k0 + 16 * EMBED),  LDSP(Bl + wave * 1024 + 512), 16, 0, 0);
        __syncthreads();
        bf16x8 af[4], bfr[4];
        #pragma unroll
        for (int m = 0; m < 4; m++) af[m]  = *(const bf16x8*)&Al[(wr * 64 + m * 16 + l15) * 32 + l4 * 8];
        #pragma unroll
        for (int n = 0; n < 4; n++) bfr[n] = *(const bf16x8*)&Bl[(wc * 64 + n * 16 + l15) * 32 + l4 * 8];
        #pragma unroll
        for (int m = 0; m < 4; m++)
            #pragma unroll
            for (int n = 0; n < 4; n++)
                acc[m][n] = MFMA(af[m], bfr[n], acc[m][n]);
    }

    const int cb = tc + wc * 64;          // wave col base; one head per wave
    const int s = cb >> 10;               // 0=q 1=k 2=v
    const int h = (cb >> 6) & 15;
    if (s < 2) {
        #pragma unroll
        for (int m = 0; m < 4; m++)
            #pragma unroll
            for (int j = 0; j < 4; j++) {
                int row = tm + wr * 64 + m * 16 + l4 * 4 + j;
                int b = row >> 11, pos = row & (SEQ - 1);
                float v[4];
                #pragma unroll
                for (int n = 0; n < 4; n++) v[n] = acc[m][n][j] + bias[cb + n * 16 + l15];
                float o[4];
                #pragma unroll
                for (int p = 0; p < 2; p++) {
                    int d1 = p * 16 + l15;
                    float c1 = rc[pos * HD + d1],      s1 = rs[pos * HD + d1];
                    float c2 = rc[pos * HD + d1 + 32], s2 = rs[pos * HD + d1 + 32];
                    o[p]     = v[p] * c1     - v[p + 2] * s1;   // d < 32 : q*cos - q[d+32]*sin
                    o[p + 2] = v[p + 2] * c2 + v[p] * s2;       // d >= 32: q*cos + q[d-32]*sin
                }
                float mul = (s == 0) ? 0.125f : 1.0f;           // fold 1/sqrt(64) into Q (exact in bf16)
                unsigned short* dst = (s == 0 ? Qb : Kb) + ((size_t)(b * NHEAD + h) * SEQ + pos) * HD;
                #pragma unroll
                for (int n = 0; n < 4; n++) dst[n * 16 + l15] = (unsigned short)f2bf(o[n] * mul);
            }
    } else {
        #pragma unroll
        for (int m = 0; m < 4; m++) {
            int row0 = tm + wr * 64 + m * 16 + l4 * 4;
            int b = row0 >> 11, pos0 = row0 & (SEQ - 1);
            #pragma unroll
            for (int n = 0; n < 4; n++) {
                float bb = bias[cb + n * 16 + l15];
                u32x2 w = { pack2(acc[m][n][0] + bb, acc[m][n][1] + bb),
                            pack2(acc[m][n][2] + bb, acc[m][n][3] + bb) };
                *(u32x2*)(Vt + ((size_t)(b * NHEAD + h) * HD + n * 16 + l15) * SEQ + pos0) = w;
            }
        }
    }
}

// ---------------- flash attention: Q,K [bh][n][64] (Q pre-scaled), V^T [bh][64][n] -> O [b*n][h*64+d] bf16 ----------------
__global__ __launch_bounds__(256) void k_attn(const unsigned short* __restrict__ Qb,
    const unsigned short* __restrict__ Kb, const unsigned short* __restrict__ Vt,
    unsigned short* __restrict__ O)
{
    __shared__ unsigned short Kl[64 * 64];   // [k][d], XOR-swizzled rows (128B)
    __shared__ unsigned short Vl[64 * 64];   // [d][tok], XOR-swizzled
    __shared__ unsigned short Pl[128 * 64];  // per-wave P [q][k], XOR-swizzled
    const int tid = threadIdx.x, wave = tid >> 6, lane = tid & 63;
    const int l15 = lane & 15, l4 = lane >> 4;
    const int bh = blockIdx.y;
    const int b = bh >> 4, h = bh & 15;
    const int q0 = blockIdx.x * 128 + wave * 32;

    // Q fragments in registers (B-operand: lane&15 = q row, walks d)
    const unsigned short* Qg = Qb + ((size_t)bh * SEQ + q0) * HD;
    bf16x8 qf[2][2];
    #pragma unroll
    for (int qb = 0; qb < 2; qb++)
        #pragma unroll
        for (int ds = 0; ds < 2; ds++)
            qf[qb][ds] = *(const bf16x8*)(Qg + (qb * 16 + l15) * HD + ds * 32 + l4 * 8);

    // staging: pre-swizzled global source so linear global_load_lds yields swizzled LDS (rule 21)
    const int srow = lane >> 3;                       // 0..7
    const int selem = ((lane & 7) * 8) ^ ((srow & 7) * 8);
    const unsigned short* kg = Kb + (size_t)bh * SEQ * HD + (size_t)(wave * 16 + srow) * HD + selem;
    const unsigned short* vg = Vt + (size_t)bh * HD * SEQ + (size_t)(wave * 16 + srow) * SEQ + selem;

    f32x4 accO[2][4] = {};
    float mst[2] = { -1e30f, -1e30f }, lst[2] = { 0.f, 0.f };

    for (int kt = 0; kt < SEQ; kt += 64) {
        __syncthreads();
        __builtin_amdgcn_global_load_lds(GLB(kg + (size_t)kt * HD),        LDSP(Kl + wave * 1024),       16, 0, 0);
        __builtin_amdgcn_global_load_lds(GLB(kg + (size_t)(kt + 8) * HD),  LDSP(Kl + wave * 1024 + 512), 16, 0, 0);
        __builtin_amdgcn_global_load_lds(GLB(vg + kt),                     LDSP(Vl + wave * 1024),       16, 0, 0);
        __builtin_amdgcn_global_load_lds(GLB(vg + 8 * SEQ + kt),           LDSP(Vl + wave * 1024 + 512), 16, 0, 0);
        __syncthreads();

        // S^T = mfma(K, Q): D[k][q], col q = lane&15, row k = kb*16 + l4*4 + r
        f32x4 sacc[2][4] = {};
        __builtin_amdgcn_s_setprio(1);
        #pragma unroll
        for (int ds = 0; ds < 2; ds++)
            #pragma unroll
            for (int kb = 0; kb < 4; kb++) {
                int krow = kb * 16 + l15;
                bf16x8 kf = *(const bf16x8*)((const char*)Kl + krow * 128 + ((ds * 64 + l4 * 16) ^ ((krow & 7) << 4)));
                sacc[0][kb] = MFMA(kf, qf[0][ds], sacc[0][kb]);
                sacc[1][kb] = MFMA(kf, qf[1][ds], sacc[1][kb]);
            }
        __builtin_amdgcn_s_setprio(0);

        // online softmax, per lane: 16 k-values for q = qb*16 + l15
        #pragma unroll
        for (int qb = 0; qb < 2; qb++) {
            float pm = -1e30f;
            #pragma unroll
            for (int kb = 0; kb < 4; kb++)
                #pragma unroll
                for (int r = 0; r < 4; r++) pm = fmaxf(pm, sacc[qb][kb][r]);
            pm = fmaxf(pm, __shfl_xor(pm, 16));
            pm = fmaxf(pm, __shfl_xor(pm, 32));
            float mnew = fmaxf(mst[qb], pm);
            float corr = __expf(mst[qb] - mnew);
            mst[qb] = mnew;
            float ls = 0.f;
            unsigned int pw[4][2];
            #pragma unroll
            for (int kb = 0; kb < 4; kb++) {
                float p0 = __expf(sacc[qb][kb][0] - mnew);
                float p1 = __expf(sacc[qb][kb][1] - mnew);
                float p2 = __expf(sacc[qb][kb][2] - mnew);
                float p3 = __expf(sacc[qb][kb][3] - mnew);
                ls += (p0 + p1) + (p2 + p3);
                pw[kb][0] = pack2(p0, p1);
                pw[kb][1] = pack2(p2, p3);
            }
            ls += __shfl_xor(ls, 16);
            ls += __shfl_xor(ls, 32);
            lst[qb] = lst[qb] * corr + ls;
            #pragma unroll
            for (int db = 0; db < 4; db++) accO[qb][db] *= corr;
            int prow = wave * 32 + qb * 16 + l15;
            #pragma unroll
            for (int kb = 0; kb < 4; kb++) {
                int pbyte = prow * 128 + ((kb * 32 + l4 * 8) ^ ((prow & 7) << 4));
                u32x2 w = { pw[kb][0], pw[kb][1] };
                *(u32x2*)((char*)Pl + pbyte) = w;   // per-wave region: no barrier needed
            }
        }

        // O^T += mfma(V^T, P): D[d][q]
        __builtin_amdgcn_s_setprio(1);
        #pragma unroll
        for (int ds = 0; ds < 2; ds++) {
            int prow0 = wave * 32 + l15, prow1 = prow0 + 16;
            bf16x8 pf0 = *(const bf16x8*)((const char*)Pl + prow0 * 128 + ((ds * 64 + l4 * 16) ^ ((prow0 & 7) << 4)));
            bf16x8 pf1 = *(const bf16x8*)((const char*)Pl + prow1 * 128 + ((ds * 64 + l4 * 16) ^ ((prow1 & 7) << 4)));
            #pragma unroll
            for (int db = 0; db < 4; db++) {
                int vrow = db * 16 + l15;
                bf16x8 vf = *(const bf16x8*)((const char*)Vl + vrow * 128 + ((ds * 64 + l4 * 16) ^ ((vrow & 7) << 4)));
                accO[0][db] = MFMA(vf, pf0, accO[0][db]);
                accO[1][db] = MFMA(vf, pf1, accO[1][db]);
            }
        }
        __builtin_amdgcn_s_setprio(0);
    }

    #pragma unroll
    for (int qb = 0; qb < 2; qb++) {
        float inv = 1.f / lst[qb];
        int tok = q0 + qb * 16 + l15;
        size_t rowo = ((size_t)b * SEQ + tok) * EMBED + h * HD;
        #pragma unroll
        for (int db = 0; db < 4; db++) {
            u32x2 w = { pack2(accO[qb][db][0] * inv, accO[qb][db][1] * inv),
                        pack2(accO[qb][db][2] * inv, accO[qb][db][3] * inv) };
            *(u32x2*)(O + rowo + db * 16 + l4 * 4) = w;
        }
    }
}

// ---------------- proj GEMM: O bf16 [8192][1024] @ Wproj^T + bias -> fp32 out ----------------
__global__ __launch_bounds__(256) void k_proj(const unsigned short* __restrict__ A,
    const unsigned short* __restrict__ wt, const float* __restrict__ bias, float* __restrict__ out)
{
    __shared__ unsigned short Al[128 * 32];
    __shared__ unsigned short Bl[128 * 32];
    const int tid = threadIdx.x;
    const int wave = tid >> 6, lane = tid & 63;
    const int l15 = lane & 15, l4 = lane >> 4;
    const int wr = wave >> 1, wc = wave & 1;
    const int tm = blockIdx.y * 128, tc = blockIdx.x * 128;

    const int srow = wave * 32 + (lane >> 2);
    const int scol = (lane & 3) * 8;
    const unsigned short* ga = A  + (size_t)(tm + srow) * EMBED + scol;
    const unsigned short* gb = wt + (size_t)(tc + srow) * EMBED + scol;

    f32x4 acc[4][4] = {};
    for (int k0 = 0; k0 < EMBED; k0 += 32) {
        __syncthreads();
        __builtin_amdgcn_global_load_lds(GLB(ga + k0),              LDSP(Al + wave * 1024),       16, 0, 0);
        __builtin_amdgcn_global_load_lds(GLB(ga + k0 + 16 * EMBED), LDSP(Al + wave * 1024 + 512), 16, 0, 0);
        __builtin_amdgcn_global_load_lds(GLB(gb + k0),              LDSP(Bl + wave * 1024),       16, 0, 0);
        __builtin_amdgcn_global_load_lds(GLB(gb + k0 + 16 * EMBED), LDSP(Bl + wave * 1024 + 512), 16, 0, 0);
        __syncthreads();
        bf16x8 af[4], bfr[4];
        #pragma unroll
        for (int m = 0; m < 4; m++) af[m]  = *(const bf16x8*)&Al[(wr * 64 + m * 16 + l15) * 32 + l4 * 8];
        #pragma unroll
        for (int n = 0; n < 4; n++) bfr[n] = *(const bf16x8*)&Bl[(wc * 64 + n * 16 + l15) * 32 + l4 * 8];
        #pragma unroll
        for (int m = 0; m < 4; m++)
            #pragma unroll
            for (int n = 0; n < 4; n++)
                acc[m][n] = MFMA(af[m], bfr[n], acc[m][n]);
    }

    #pragma unroll
    for (int m = 0; m < 4; m++)
        #pragma unroll
        for (int j = 0; j < 4; j++) {
            int row = tm + wr * 64 + m * 16 + l4 * 4 + j;
            #pragma unroll
            for (int n = 0; n < 4; n++) {
                int col = tc + wc * 64 + n * 16 + l15;
                out[(size_t)row * EMBED + col] = acc[m][n][j] + bias[col];
            }
        }
}

extern "C" void kernel_launch(void* const* d_in, const int* in_sizes, int n_in,
                              void* d_out, int out_size, void* d_ws, size_t ws_size,
                              hipStream_t stream) {
    const float* x     = (const float*)d_in[0];
    const float* rc    = (const float*)d_in[1];
    const float* rs    = (const float*)d_in[2];
    const float* Wqkv  = (const float*)d_in[3];
    const float* bqkv  = (const float*)d_in[4];
    const float* Wproj = (const float*)d_in[5];
    const float* bproj = (const float*)d_in[6];
    char* ws = (char*)d_ws;
    // workspace layout (75.5 MB): xb region is reused for attention output
    unsigned short* xb  = (unsigned short*)(ws);                 // 16.78MB : x bf16, later attn-O bf16
    unsigned short* wqt = (unsigned short*)(ws + 16777216);      //  6.29MB : Wqkv^T bf16
    unsigned short* wpt = (unsigned short*)(ws + 23068672);      //  2.10MB : Wproj^T bf16
    unsigned short* Qb  = (unsigned short*)(ws + 25165824);      // 16.78MB : Q (roped, prescaled)
    unsigned short* Kb  = (unsigned short*)(ws + 41943040);      // 16.78MB : K (roped)
    unsigned short* Vt  = (unsigned short*)(ws + 58720256);      // 16.78MB : V^T
    float* outp = (float*)d_out;

    k_convert  <<<8192, 256, 0, stream>>>(x, xb, 2097152);
    k_transpose<<<dim3(96, 32), 256, 0, stream>>>(Wqkv, wqt, 1024, 3072);
    k_transpose<<<dim3(32, 32), 256, 0, stream>>>(Wproj, wpt, 1024, 1024);
    k_qkv      <<<dim3(24, 64), 256, 0, stream>>>(xb, wqt, bqkv, rc, rs, Qb, Kb, Vt);
    k_attn     <<<dim3(16, 64), 256, 0, stream>>>(Qb, Kb, Vt, xb);
    k_proj     <<<dim3(8, 64),  256, 0, stream>>>(xb, wpt, bproj, outp);
}

// Round 3
// 336.377 us; speedup vs baseline: 1.0375x; 1.0375x over previous
//
#include <hip/hip_runtime.h>
#include <stdint.h>

#define EMBED 1024
#define NHEAD 16
#define HD    64
#define SEQ   2048
#define BATCH 4

typedef __bf16 bf16x8 __attribute__((ext_vector_type(8)));
typedef __bf16 bf16x4 __attribute__((ext_vector_type(4)));
typedef float  f32x4  __attribute__((ext_vector_type(4)));
typedef unsigned int u32x2 __attribute__((ext_vector_type(2)));

#define GLB(p)  ((__attribute__((address_space(1))) unsigned int*)(p))
#define LDSP(p) ((__attribute__((address_space(3))) unsigned int*)(p))
#define MFMA(a,b,c) __builtin_amdgcn_mfma_f32_16x16x32_bf16(a,b,c,0,0,0)
#define EXP2(x) __builtin_amdgcn_exp2f(x)

// Q pre-scale: (1/sqrt(64)) * log2(e) so attention probs are exp2(S - m) directly
#define QSCALE 0.18033688011112042f

__device__ __forceinline__ unsigned int f2bf(float f) {
    unsigned int u = __float_as_uint(f);
    return (u + 0x7FFFu + ((u >> 16) & 1u)) >> 16;   // RNE fp32->bf16
}
__device__ __forceinline__ unsigned int pack2(float a, float b) {
    return f2bf(a) | (f2bf(b) << 16);
}

// ---------------- x fp32 -> bf16 ----------------
__global__ void k_convert(const float* __restrict__ in, unsigned short* __restrict__ out, int n4) {
    int i = blockIdx.x * 256 + threadIdx.x;
    if (i >= n4) return;
    f32x4 v = ((const f32x4*)in)[i];
    u32x2 w = { pack2(v[0], v[1]), pack2(v[2], v[3]) };
    ((u32x2*)out)[i] = w;
}

// ---------------- W [K][C] fp32 -> Wt [C][K] bf16 (LDS-tiled transpose) ----------------
__global__ void k_transpose(const float* __restrict__ in, unsigned short* __restrict__ out, int K, int C) {
    __shared__ float t[32][33];
    int c0 = blockIdx.x * 32, k0 = blockIdx.y * 32;
    int tid = threadIdx.x;
    #pragma unroll
    for (int i = 0; i < 4; i++) {
        int e = tid + i * 256;
        t[e >> 5][e & 31] = in[(size_t)(k0 + (e >> 5)) * C + c0 + (e & 31)];
    }
    __syncthreads();
    #pragma unroll
    for (int i = 0; i < 4; i++) {
        int e = tid + i * 256;
        int cl = e >> 5, kl = e & 31;
        out[(size_t)(c0 + cl) * K + k0 + kl] = (unsigned short)f2bf(t[kl][cl]);
    }
}

// ---------------- QKV GEMM + bias + RoPE, writes Q,K [bh][n][64] (Q pre-scaled by QSCALE), V^T [bh][64][n] ----------------
__global__ __launch_bounds__(256) void k_qkv(const unsigned short* __restrict__ xb,
    const unsigned short* __restrict__ wt, const float* __restrict__ bias,
    const float* __restrict__ rc, const float* __restrict__ rs,
    unsigned short* __restrict__ Qb, unsigned short* __restrict__ Kb, unsigned short* __restrict__ Vt)
{
    __shared__ unsigned short Al[128 * 32];
    __shared__ unsigned short Bl[128 * 32];
    const int tid = threadIdx.x;
    const int wave = tid >> 6, lane = tid & 63;
    const int l15 = lane & 15, l4 = lane >> 4;
    const int wr = wave >> 1, wc = wave & 1;
    const int tm = blockIdx.y * 128, tc = blockIdx.x * 128;

    const int srow = wave * 32 + (lane >> 2);
    const int scol = (lane & 3) * 8;
    const unsigned short* ga = xb + (size_t)(tm + srow) * EMBED + scol;
    const unsigned short* gb = wt + (size_t)(tc + srow) * EMBED + scol;

    f32x4 acc[4][4] = {};
    for (int k0 = 0; k0 < EMBED; k0 += 32) {
        __syncthreads();
        __builtin_amdgcn_global_load_lds(GLB(ga + k0),               LDSP(Al + wave * 1024),       16, 0, 0);
        __builtin_amdgcn_global_load_lds(GLB(ga + k0 + 16 * EMBED),  LDSP(Al + wave * 1024 + 512), 16, 0, 0);
        __builtin_amdgcn_global_load_lds(GLB(gb + k0),               LDSP(Bl + wave * 1024),       16, 0, 0);
        __builtin_amdgcn_global_load_lds(GLB(gb + k0 + 16 * EMBED),  LDSP(Bl + wave * 1024 + 512), 16, 0, 0);
        __syncthreads();
        bf16x8 af[4], bfr[4];
        #pragma unroll
        for (int m = 0; m < 4; m++) af[m]  = *(const bf16x8*)&Al[(wr * 64 + m * 16 + l15) * 32 + l4 * 8];
        #pragma unroll
        for (int n = 0; n < 4; n++) bfr[n] = *(const bf16x8*)&Bl[(wc * 64 + n * 16 + l15) * 32 + l4 * 8];
        #pragma unroll
        for (int m = 0; m < 4; m++)
            #pragma unroll
            for (int n = 0; n < 4; n++)
                acc[m][n] = MFMA(af[m], bfr[n], acc[m][n]);
    }

    const int cb = tc + wc * 64;          // wave col base; one head per wave
    const int s = cb >> 10;               // 0=q 1=k 2=v
    const int h = (cb >> 6) & 15;
    if (s < 2) {
        #pragma unroll
        for (int m = 0; m < 4; m++)
            #pragma unroll
            for (int j = 0; j < 4; j++) {
                int row = tm + wr * 64 + m * 16 + l4 * 4 + j;
                int b = row >> 11, pos = row & (SEQ - 1);
                float v[4];
                #pragma unroll
                for (int n = 0; n < 4; n++) v[n] = acc[m][n][j] + bias[cb + n * 16 + l15];
                float o[4];
                #pragma unroll
                for (int p = 0; p < 2; p++) {
                    int d1 = p * 16 + l15;
                    float c1 = rc[pos * HD + d1],      s1 = rs[pos * HD + d1];
                    float c2 = rc[pos * HD + d1 + 32], s2 = rs[pos * HD + d1 + 32];
                    o[p]     = v[p] * c1     - v[p + 2] * s1;   // d < 32 : q*cos - q[d+32]*sin
                    o[p + 2] = v[p + 2] * c2 + v[p] * s2;       // d >= 32: q*cos + q[d-32]*sin
                }
                float mul = (s == 0) ? QSCALE : 1.0f;           // fold 1/sqrt(64)*log2e into Q
                unsigned short* dst = (s == 0 ? Qb : Kb) + ((size_t)(b * NHEAD + h) * SEQ + pos) * HD;
                #pragma unroll
                for (int n = 0; n < 4; n++) dst[n * 16 + l15] = (unsigned short)f2bf(o[n] * mul);
            }
    } else {
        #pragma unroll
        for (int m = 0; m < 4; m++) {
            int row0 = tm + wr * 64 + m * 16 + l4 * 4;
            int b = row0 >> 11, pos0 = row0 & (SEQ - 1);
            #pragma unroll
            for (int n = 0; n < 4; n++) {
                float bb = bias[cb + n * 16 + l15];
                u32x2 w = { pack2(acc[m][n][0] + bb, acc[m][n][1] + bb),
                            pack2(acc[m][n][2] + bb, acc[m][n][3] + bb) };
                *(u32x2*)(Vt + ((size_t)(b * NHEAD + h) * HD + n * 16 + l15) * SEQ + pos0) = w;
            }
        }
    }
}

// ---------------- flash attention: Q,K [bh][n][64] (Q pre-scaled), V^T [bh][64][n] -> O [b*n][h*64+d] bf16 ----------------
__global__ __launch_bounds__(256) void k_attn(const unsigned short* __restrict__ Qb,
    const unsigned short* __restrict__ Kb, const unsigned short* __restrict__ Vt,
    unsigned short* __restrict__ O)
{
    __shared__ unsigned short Kl[64 * 64];   // [k][d], XOR-swizzled rows (128B)
    __shared__ unsigned short Vl[64 * 64];   // [d][tok], XOR-swizzled
    __shared__ unsigned short Pl[128 * 64];  // per-wave P [q][k], XOR-swizzled
    const int tid = threadIdx.x, wave = tid >> 6, lane = tid & 63;
    const int l15 = lane & 15, l4 = lane >> 4;
    const int bh = blockIdx.y;
    const int b = bh >> 4, h = bh & 15;
    const int q0 = blockIdx.x * 128 + wave * 32;

    // Q fragments in registers (B-operand: lane&15 = q row, walks d)
    const unsigned short* Qg = Qb + ((size_t)bh * SEQ + q0) * HD;
    bf16x8 qf[2][2];
    #pragma unroll
    for (int qb = 0; qb < 2; qb++)
        #pragma unroll
        for (int ds = 0; ds < 2; ds++)
            qf[qb][ds] = *(const bf16x8*)(Qg + (qb * 16 + l15) * HD + ds * 32 + l4 * 8);

    // staging: pre-swizzled global source so linear global_load_lds yields swizzled LDS (rule 21)
    const int srow = lane >> 3;                       // 0..7
    const int selem = ((lane & 7) * 8) ^ ((srow & 7) * 8);
    const unsigned short* kg = Kb + (size_t)bh * SEQ * HD + (size_t)(wave * 16 + srow) * HD + selem;
    const unsigned short* vg = Vt + (size_t)bh * HD * SEQ + (size_t)(wave * 16 + srow) * SEQ + selem;

    f32x4 accO[2][4] = {};
    float mst[2] = { -1e30f, -1e30f }, lst[2] = { 0.f, 0.f };

    for (int kt = 0; kt < SEQ; kt += 64) {
        __syncthreads();
        __builtin_amdgcn_global_load_lds(GLB(kg + (size_t)kt * HD),        LDSP(Kl + wave * 1024),       16, 0, 0);
        __builtin_amdgcn_global_load_lds(GLB(kg + (size_t)(kt + 8) * HD),  LDSP(Kl + wave * 1024 + 512), 16, 0, 0);
        __builtin_amdgcn_global_load_lds(GLB(vg + kt),                     LDSP(Vl + wave * 1024),       16, 0, 0);
        __builtin_amdgcn_global_load_lds(GLB(vg + 8 * SEQ + kt),           LDSP(Vl + wave * 1024 + 512), 16, 0, 0);
        __syncthreads();

        // S^T = mfma(K, Q): D[k][q], col q = lane&15, row k = kb*16 + l4*4 + r
        f32x4 sacc[2][4] = {};
        __builtin_amdgcn_s_setprio(1);
        #pragma unroll
        for (int ds = 0; ds < 2; ds++)
            #pragma unroll
            for (int kb = 0; kb < 4; kb++) {
                int krow = kb * 16 + l15;
                bf16x8 kf = *(const bf16x8*)((const char*)Kl + krow * 128 + ((ds * 64 + l4 * 16) ^ ((krow & 7) << 4)));
                sacc[0][kb] = MFMA(kf, qf[0][ds], sacc[0][kb]);
                sacc[1][kb] = MFMA(kf, qf[1][ds], sacc[1][kb]);
            }
        __builtin_amdgcn_s_setprio(0);

        // online softmax (lazy-max T13, exp2 domain), per lane: 16 k-values for q = qb*16 + l15
        #pragma unroll
        for (int qb = 0; qb < 2; qb++) {
            float pm = -1e30f;
            #pragma unroll
            for (int kb = 0; kb < 4; kb++)
                #pragma unroll
                for (int r = 0; r < 4; r++) pm = fmaxf(pm, sacc[qb][kb][r]);
            pm = fmaxf(pm, __shfl_xor(pm, 16));
            pm = fmaxf(pm, __shfl_xor(pm, 32));
            // defer-max: skip O/l rescale while tile max stays within 2^8 of running max
            bool skip = __all(pm <= mst[qb] + 8.f);
            float mnew = skip ? mst[qb] : fmaxf(mst[qb], pm);
            float ls = 0.f;
            bf16x4 pw[4];
            #pragma unroll
            for (int kb = 0; kb < 4; kb++) {
                float p0 = EXP2(sacc[qb][kb][0] - mnew);
                float p1 = EXP2(sacc[qb][kb][1] - mnew);
                float p2 = EXP2(sacc[qb][kb][2] - mnew);
                float p3 = EXP2(sacc[qb][kb][3] - mnew);
                ls += (p0 + p1) + (p2 + p3);
                pw[kb][0] = (__bf16)p0; pw[kb][1] = (__bf16)p1;   // compiler emits v_cvt_pk_bf16_f32
                pw[kb][2] = (__bf16)p2; pw[kb][3] = (__bf16)p3;
            }
            ls += __shfl_xor(ls, 16);
            ls += __shfl_xor(ls, 32);
            if (skip) {
                lst[qb] += ls;
            } else {
                float corr = EXP2(mst[qb] - mnew);
                mst[qb] = mnew;
                lst[qb] = lst[qb] * corr + ls;
                #pragma unroll
                for (int db = 0; db < 4; db++) accO[qb][db] *= corr;
            }
            int prow = wave * 32 + qb * 16 + l15;
            #pragma unroll
            for (int kb = 0; kb < 4; kb++) {
                int pbyte = prow * 128 + ((kb * 32 + l4 * 8) ^ ((prow & 7) << 4));
                *(bf16x4*)((char*)Pl + pbyte) = pw[kb];   // per-wave region: no barrier needed
            }
        }

        // O^T += mfma(V^T, P): D[d][q]
        __builtin_amdgcn_s_setprio(1);
        #pragma unroll
        for (int ds = 0; ds < 2; ds++) {
            int prow0 = wave * 32 + l15, prow1 = prow0 + 16;
            bf16x8 pf0 = *(const bf16x8*)((const char*)Pl + prow0 * 128 + ((ds * 64 + l4 * 16) ^ ((prow0 & 7) << 4)));
            bf16x8 pf1 = *(const bf16x8*)((const char*)Pl + prow1 * 128 + ((ds * 64 + l4 * 16) ^ ((prow1 & 7) << 4)));
            #pragma unroll
            for (int db = 0; db < 4; db++) {
                int vrow = db * 16 + l15;
                bf16x8 vf = *(const bf16x8*)((const char*)Vl + vrow * 128 + ((ds * 64 + l4 * 16) ^ ((vrow & 7) << 4)));
                accO[0][db] = MFMA(vf, pf0, accO[0][db]);
                accO[1][db] = MFMA(vf, pf1, accO[1][db]);
            }
        }
        __builtin_amdgcn_s_setprio(0);
    }

    #pragma unroll
    for (int qb = 0; qb < 2; qb++) {
        float inv = 1.f / lst[qb];
        int tok = q0 + qb * 16 + l15;
        size_t rowo = ((size_t)b * SEQ + tok) * EMBED + h * HD;
        #pragma unroll
        for (int db = 0; db < 4; db++) {
            u32x2 w = { pack2(accO[qb][db][0] * inv, accO[qb][db][1] * inv),
                        pack2(accO[qb][db][2] * inv, accO[qb][db][3] * inv) };
            *(u32x2*)(O + rowo + db * 16 + l4 * 4) = w;
        }
    }
}

// ---------------- proj GEMM: O bf16 [8192][1024] @ Wproj^T + bias -> fp32 out ----------------
__global__ __launch_bounds__(256) void k_proj(const unsigned short* __restrict__ A,
    const unsigned short* __restrict__ wt, const float* __restrict__ bias, float* __restrict__ out)
{
    __shared__ unsigned short Al[128 * 32];
    __shared__ unsigned short Bl[128 * 32];
    const int tid = threadIdx.x;
    const int wave = tid >> 6, lane = tid & 63;
    const int l15 = lane & 15, l4 = lane >> 4;
    const int wr = wave >> 1, wc = wave & 1;
    const int tm = blockIdx.y * 128, tc = blockIdx.x * 128;

    const int srow = wave * 32 + (lane >> 2);
    const int scol = (lane & 3) * 8;
    const unsigned short* ga = A  + (size_t)(tm + srow) * EMBED + scol;
    const unsigned short* gb = wt + (size_t)(tc + srow) * EMBED + scol;

    f32x4 acc[4][4] = {};
    for (int k0 = 0; k0 < EMBED; k0 += 32) {
        __syncthreads();
        __builtin_amdgcn_global_load_lds(GLB(ga + k0),              LDSP(Al + wave * 1024),       16, 0, 0);
        __builtin_amdgcn_global_load_lds(GLB(ga + k0 + 16 * EMBED), LDSP(Al + wave * 1024 + 512), 16, 0, 0);
        __builtin_amdgcn_global_load_lds(GLB(gb + k0),              LDSP(Bl + wave * 1024),       16, 0, 0);
        __builtin_amdgcn_global_load_lds(GLB(gb + k0 + 16 * EMBED), LDSP(Bl + wave * 1024 + 512), 16, 0, 0);
        __syncthreads();
        bf16x8 af[4], bfr[4];
        #pragma unroll
        for (int m = 0; m < 4; m++) af[m]  = *(const bf16x8*)&Al[(wr * 64 + m * 16 + l15) * 32 + l4 * 8];
        #pragma unroll
        for (int n = 0; n < 4; n++) bfr[n] = *(const bf16x8*)&Bl[(wc * 64 + n * 16 + l15) * 32 + l4 * 8];
        #pragma unroll
        for (int m = 0; m < 4; m++)
            #pragma unroll
            for (int n = 0; n < 4; n++)
                acc[m][n] = MFMA(af[m], bfr[n], acc[m][n]);
    }

    #pragma unroll
    for (int m = 0; m < 4; m++)
        #pragma unroll
        for (int j = 0; j < 4; j++) {
            int row = tm + wr * 64 + m * 16 + l4 * 4 + j;
            #pragma unroll
            for (int n = 0; n < 4; n++) {
                int col = tc + wc * 64 + n * 16 + l15;
                out[(size_t)row * EMBED + col] = acc[m][n][j] + bias[col];
            }
        }
}

extern "C" void kernel_launch(void* const* d_in, const int* in_sizes, int n_in,
                              void* d_out, int out_size, void* d_ws, size_t ws_size,
                              hipStream_t stream) {
    const float* x     = (const float*)d_in[0];
    const float* rc    = (const float*)d_in[1];
    const float* rs    = (const float*)d_in[2];
    const float* Wqkv  = (const float*)d_in[3];
    const float* bqkv  = (const float*)d_in[4];
    const float* Wproj = (const float*)d_in[5];
    const float* bproj = (const float*)d_in[6];
    char* ws = (char*)d_ws;
    // workspace layout (75.5 MB): xb region is reused for attention output
    unsigned short* xb  = (unsigned short*)(ws);                 // 16.78MB : x bf16, later attn-O bf16
    unsigned short* wqt = (unsigned short*)(ws + 16777216);      //  6.29MB : Wqkv^T bf16
    unsigned short* wpt = (unsigned short*)(ws + 23068672);      //  2.10MB : Wproj^T bf16
    unsigned short* Qb  = (unsigned short*)(ws + 25165824);      // 16.78MB : Q (roped, prescaled by QSCALE)
    unsigned short* Kb  = (unsigned short*)(ws + 41943040);      // 16.78MB : K (roped)
    unsigned short* Vt  = (unsigned short*)(ws + 58720256);      // 16.78MB : V^T
    float* outp = (float*)d_out;

    k_convert  <<<8192, 256, 0, stream>>>(x, xb, 2097152);
    k_transpose<<<dim3(96, 32), 256, 0, stream>>>(Wqkv, wqt, 1024, 3072);
    k_transpose<<<dim3(32, 32), 256, 0, stream>>>(Wproj, wpt, 1024, 1024);
    k_qkv      <<<dim3(24, 64), 256, 0, stream>>>(xb, wqt, bqkv, rc, rs, Qb, Kb, Vt);
    k_attn     <<<dim3(16, 64), 256, 0, stream>>>(Qb, Kb, Vt, xb);
    k_proj     <<<dim3(8, 64),  256, 0, stream>>>(xb, wpt, bproj, outp);
}